// Round 11
// baseline (244.461 us; speedup 1.0000x reference)
//
#include <hip/hip_runtime.h>

#define BB 1024
#define VV 6890
#define NJ 24
#define NBETA 10
#define PF 207            // (J-1)*9
#define V3 (VV*3)         // 20670
#define KP 224            // GEMM1 K: 207 pose + 10 shape + 2 vtemp(hi/lo) + 5 zero
#define VTB 64            // vertices per block tile in k_main
#define NVT ((VV + VTB - 1) / VTB)   // 108
#define VPAD (NVT * VTB)             // 6912 rows per component in pdT
#define K2 32             // GEMM2 K: 24 joints + 1 transl-one + 7 zero
#define NCHK 24           // jreg chunks (one block each, all joints)
#define CHV 288           // verts per chunk (24*288 >= 6890)
#define NBLK_A (NVT * 4)             // 432: (v-block, k-quarter)
#define NBLK_B (VPAD / 256)          // 27
#define NBLK_C NCHK                  // 24
#define NBT 4             // batch-tiles per k_main block
#define XSW 52            // xls per-wave stride (dwords): [batch][c*16+vert]
#define TSW 198           // Tls per-wave stride (u16):   [vert][be]
#define NWG (16 * NVT)    // 1728 k_main workgroups

typedef float f32x4 __attribute__((ext_vector_type(4)));
typedef short s16x8 __attribute__((ext_vector_type(8)));
typedef short s16x4 __attribute__((ext_vector_type(4)));

__device__ __constant__ int kParents[NJ] = {-1,0,0,0,1,2,3,4,5,6,7,8,9,9,9,12,13,14,16,17,18,19,20,21};

__device__ __forceinline__ unsigned short f2bf(float x) {
    unsigned int u = __float_as_uint(x);
    unsigned int r = (u + 0x7fffu + ((u >> 16) & 1u)) >> 16;
    return (unsigned short)r;
}
__device__ __forceinline__ float bf2f(unsigned short h) {
    return __uint_as_float((unsigned int)h << 16);
}

// ---------------------------------------------------------------------------
// k_prep_all: 3 block-ranges:
//  A [0,432):    pdT rows, COMPONENT-MAJOR (row = c*VPAD+v), 4-way k-split,
//                LDS-staged transpose (coalesced loads, 16B stores).
//  B [432,459):  lbswB rows — GEMM2 operand (w(24) | 1.0 | 0(7))
//  C [459,483):  jreg partials — one block per vert-chunk, ALL joints
//                (sdirs read once from HBM, L2-resident across joints).
// ---------------------------------------------------------------------------
__global__ __launch_bounds__(256) void k_prep_all(
    const float* __restrict__ pdirs,     // (207, V3)
    const float* __restrict__ sdirs,     // (V3, 10)
    const float* __restrict__ vtemp,     // (V3)
    const float* __restrict__ lbsw,      // (V, 24)
    const float* __restrict__ Jreg,      // (24, V)
    unsigned short* __restrict__ pdT,    // (3*VPAD, KP) component-major
    unsigned short* __restrict__ lbswB,  // (VPAD, K2)
    float* __restrict__ jpart)           // (24, NCHK, 33)
{
    int bid = blockIdx.x;
    int t = threadIdx.x;

    if (bid < NBLK_A) {
        int vb = bid >> 2;              // v-block 0..107
        int kq = bid & 3;               // k-quarter 0..3
        int kc0 = kq * 56;
        int v0 = vb * 64;
        __shared__ unsigned short tileA[3][56][65];   // 21840 B

        int ksub = t >> 6;              // 0..3
        int vo   = t & 63;
        int v    = v0 + vo;
        bool valid = v < VV;
        int v3b  = v * 3;
#pragma unroll
        for (int i = 0; i < 14; ++i) {
            int kl = ksub * 14 + i;     // 0..55
            int k  = kc0 + kl;
            float c0 = 0.f, c1 = 0.f, c2 = 0.f;
            if (valid) {
                if (k < PF) {
                    const float* p = pdirs + (size_t)k * V3 + v3b;
                    c0 = p[0]; c1 = p[1]; c2 = p[2];
                } else if (k < PF + NBETA) {
                    int l = k - PF;
                    c0 = sdirs[(size_t)(v3b + 0) * NBETA + l];
                    c1 = sdirs[(size_t)(v3b + 1) * NBETA + l];
                    c2 = sdirs[(size_t)(v3b + 2) * NBETA + l];
                } else if (k == PF + NBETA) {
                    c0 = vtemp[v3b]; c1 = vtemp[v3b + 1]; c2 = vtemp[v3b + 2];
                } else if (k == PF + NBETA + 1) {
                    float x0 = vtemp[v3b], x1 = vtemp[v3b + 1], x2 = vtemp[v3b + 2];
                    c0 = x0 - bf2f(f2bf(x0));
                    c1 = x1 - bf2f(f2bf(x1));
                    c2 = x2 - bf2f(f2bf(x2));
                }
            }
            tileA[0][kl][vo] = f2bf(c0);
            tileA[1][kl][vo] = f2bf(c1);
            tileA[2][kl][vo] = f2bf(c2);
        }
        __syncthreads();

        int vo2 = t >> 2;               // 0..63
        int sub = t & 3;
#pragma unroll
        for (int c = 0; c < 3; ++c) {
#pragma unroll
            for (int j = 0; j < 2; ++j) {
                int ch = sub + 4 * j;   // 0..7, need 0..6 (7 chunks x 8 = 56)
                if (ch < 7) {
                    union { s16x8 v8; unsigned short u[8]; } pk;
#pragma unroll
                    for (int i = 0; i < 8; ++i) pk.u[i] = tileA[c][ch * 8 + i][vo2];
                    *(s16x8*)(pdT + (size_t)(c * VPAD + v0 + vo2) * KP
                                   + kc0 + ch * 8) = pk.v8;
                }
            }
        }
    } else if (bid < NBLK_A + NBLK_B) {
        int v = (bid - NBLK_A) * 256 + t;
        bool valid = v < VV;
        unsigned short* o = lbswB + (size_t)v * K2;
        union { s16x8 v8; unsigned short u[8]; } pk;
#pragma unroll
        for (int g = 0; g < 3; ++g) {
#pragma unroll
            for (int i = 0; i < 8; ++i)
                pk.u[i] = valid ? f2bf(lbsw[(size_t)v * NJ + g * 8 + i]) : (unsigned short)0;
            *(s16x8*)(o + g * 8) = pk.v8;
        }
        pk.u[0] = 0x3F80;               // col 24 = 1.0 (transl K-column)
#pragma unroll
        for (int i = 1; i < 8; ++i) pk.u[i] = 0;
        *(s16x8*)(o + 24) = pk.v8;
    } else {
        int ch = bid - NBLK_A - NBLK_B; // 0..23
        int v0 = ch * CHV;
        int vend = min(VV, v0 + CHV);
        __shared__ float sred[33][4];
        int wave = t >> 6, lane = t & 63;

        for (int j = 0; j < NJ; ++j) {
            float acc[33];
#pragma unroll
            for (int i = 0; i < 33; ++i) acc[i] = 0.f;

            for (int v = v0 + t; v < vend; v += 256) {
                float w = Jreg[(size_t)j * VV + v];
#pragma unroll
                for (int c = 0; c < 3; ++c) {
                    acc[30 + c] += w * vtemp[v * 3 + c];
#pragma unroll
                    for (int l = 0; l < NBETA; ++l)
                        acc[c * NBETA + l] += w * sdirs[(size_t)(v * 3 + c) * NBETA + l];
                }
            }
#pragma unroll
            for (int i = 0; i < 33; ++i) {
                float x = acc[i];
                for (int off = 32; off > 0; off >>= 1) x += __shfl_down(x, off);
                acc[i] = x;
            }
            if (lane == 0) {
#pragma unroll
                for (int i = 0; i < 33; ++i) sred[i][wave] = acc[i];
            }
            __syncthreads();
            if (t == 0) {
#pragma unroll
                for (int i = 0; i < 33; ++i)
                    jpart[(size_t)(j * NCHK + ch) * 33 + i] =
                        sred[i][0] + sred[i][1] + sred[i][2] + sred[i][3];
            }
            __syncthreads();
        }
    }
}

// ---------------------------------------------------------------------------
// k_jred: reduce jpart (24, NCHK, 33) -> sJg (24*33)
// ---------------------------------------------------------------------------
__global__ __launch_bounds__(256) void k_jred(
    const float* __restrict__ jpart,
    float* __restrict__ sJg)             // (NJ*33)
{
    for (int idx = threadIdx.x; idx < NJ * 33; idx += 256) {
        int j = idx / 33, i = idx % 33;
        float s = 0.f;
#pragma unroll
        for (int c = 0; c < NCHK; ++c) s += jpart[(size_t)(j * NCHK + c) * 33 + i];
        sJg[j * 33 + i] = s;
    }
}

// ---------------------------------------------------------------------------
// k_batch: rodrigues, kinematic chain, pose features -> pfB,
// rel transforms (+transl in col 24) -> relBT, posed joints -> out.
// ---------------------------------------------------------------------------
__global__ __launch_bounds__(32) void k_batch(
    const float* __restrict__ transl,
    const float* __restrict__ orient,
    const float* __restrict__ betas,
    const float* __restrict__ bpose,
    const float* __restrict__ sJg,       // (NJ*33)
    unsigned short* __restrict__ pfB,    // (B, KP)
    unsigned short* __restrict__ relBT,  // (B*12, K2)
    float* __restrict__ joints_out)      // (B, 24, 3)
{
    int t = threadIdx.x;
    int b = blockIdx.x * 32 + t;

    __shared__ float sJ[NJ * 33];
    __shared__ float chain[NJ][12][32];

    for (int idx = t; idx < NJ * 33; idx += 32) sJ[idx] = sJg[idx];
    __syncthreads();

    float bet[NBETA];
#pragma unroll
    for (int l = 0; l < NBETA; ++l) bet[l] = betas[b * NBETA + l];

    float jx[NJ], jy[NJ], jz[NJ];
#pragma unroll
    for (int j = 0; j < NJ; ++j) {
        float a = sJ[j * 33 + 30], bb = sJ[j * 33 + 31], cc = sJ[j * 33 + 32];
#pragma unroll
        for (int l = 0; l < NBETA; ++l) {
            a  += sJ[j * 33 + l]      * bet[l];
            bb += sJ[j * 33 + 10 + l] * bet[l];
            cc += sJ[j * 33 + 20 + l] * bet[l];
        }
        jx[j] = a; jy[j] = bb; jz[j] = cc;
    }

    float tr0 = transl[b * 3 + 0], tr1 = transl[b * 3 + 1], tr2 = transl[b * 3 + 2];

    for (int j = 0; j < NJ; ++j) {
        float rx, ry, rz;
        if (j == 0) {
            rx = orient[b * 3 + 0]; ry = orient[b * 3 + 1]; rz = orient[b * 3 + 2];
        } else {
            rx = bpose[b * 69 + (j - 1) * 3 + 0];
            ry = bpose[b * 69 + (j - 1) * 3 + 1];
            rz = bpose[b * 69 + (j - 1) * 3 + 2];
        }
        float ax = rx + 1e-8f, ay = ry + 1e-8f, az = rz + 1e-8f;
        float angle = sqrtf(ax * ax + ay * ay + az * az);
        float inv = 1.f / angle;
        float kx = rx * inv, ky = ry * inv, kz = rz * inv;
        float s = sinf(angle), c = cosf(angle), omc = 1.f - c;
        float R[9];
        R[0] = 1.f - omc * (ky * ky + kz * kz);
        R[1] = -s * kz + omc * (kx * ky);
        R[2] =  s * ky + omc * (kx * kz);
        R[3] =  s * kz + omc * (kx * ky);
        R[4] = 1.f - omc * (kx * kx + kz * kz);
        R[5] = -s * kx + omc * (ky * kz);
        R[6] = -s * ky + omc * (kx * kz);
        R[7] =  s * kx + omc * (ky * kz);
        R[8] = 1.f - omc * (kx * kx + ky * ky);

        if (j > 0) {
#pragma unroll
            for (int e = 0; e < 9; ++e) {
                float val = R[e] - ((e == 0 || e == 4 || e == 8) ? 1.f : 0.f);
                pfB[(size_t)b * KP + (j - 1) * 9 + e] = f2bf(val);
            }
        }

        int p = kParents[j];
        float tx, ty, tz;
        if (j == 0) { tx = jx[0]; ty = jy[0]; tz = jz[0]; }
        else        { tx = jx[j] - jx[p]; ty = jy[j] - jy[p]; tz = jz[j] - jz[p]; }

        float A[12];
        if (j == 0) {
            A[0] = R[0]; A[1] = R[1]; A[2]  = R[2]; A[3]  = tx;
            A[4] = R[3]; A[5] = R[4]; A[6]  = R[5]; A[7]  = ty;
            A[8] = R[6]; A[9] = R[7]; A[10] = R[8]; A[11] = tz;
        } else {
            float P[12];
#pragma unroll
            for (int e = 0; e < 12; ++e) P[e] = chain[p][e][t];
#pragma unroll
            for (int r = 0; r < 3; ++r) {
#pragma unroll
                for (int cc = 0; cc < 3; ++cc)
                    A[r * 4 + cc] = P[r * 4 + 0] * R[0 * 3 + cc] +
                                    P[r * 4 + 1] * R[1 * 3 + cc] +
                                    P[r * 4 + 2] * R[2 * 3 + cc];
                A[r * 4 + 3] = P[r * 4 + 0] * tx + P[r * 4 + 1] * ty +
                               P[r * 4 + 2] * tz + P[r * 4 + 3];
            }
        }
#pragma unroll
        for (int e = 0; e < 12; ++e) chain[j][e][t] = A[e];

        joints_out[(b * NJ + j) * 3 + 0] = A[3]  + tr0;
        joints_out[(b * NJ + j) * 3 + 1] = A[7]  + tr1;
        joints_out[(b * NJ + j) * 3 + 2] = A[11] + tr2;

        float bx = A[0] * jx[j] + A[1] * jy[j] + A[2]  * jz[j];
        float by = A[4] * jx[j] + A[5] * jy[j] + A[6]  * jz[j];
        float bz = A[8] * jx[j] + A[9] * jy[j] + A[10] * jz[j];
        float relv[12];
        relv[0] = A[0]; relv[1] = A[1]; relv[2]  = A[2];  relv[3]  = A[3]  - bx;
        relv[4] = A[4]; relv[5] = A[5]; relv[6]  = A[6];  relv[7]  = A[7]  - by;
        relv[8] = A[8]; relv[9] = A[9]; relv[10] = A[10]; relv[11] = A[11] - bz;
#pragma unroll
        for (int e = 0; e < 12; ++e)
            relBT[(size_t)(b * 12 + e) * K2 + j] = f2bf(relv[e]);
    }

    // relBT tail: col 24 = transl component (paired with lbswB col24 = 1.0)
#pragma unroll
    for (int e = 0; e < 12; ++e) {
        float tv = (e == 3) ? tr0 : (e == 7) ? tr1 : (e == 11) ? tr2 : 0.f;
        relBT[(size_t)(b * 12 + e) * K2 + 24] = f2bf(tv);
#pragma unroll
        for (int j2 = NJ + 1; j2 < K2; ++j2)
            relBT[(size_t)(b * 12 + e) * K2 + j2] = 0;
    }

    // pfB tail: betas, ones (vtemp hi/lo), zero pad to KP
#pragma unroll
    for (int l = 0; l < NBETA; ++l)
        pfB[(size_t)b * KP + PF + l] = f2bf(bet[l]);
    pfB[(size_t)b * KP + PF + NBETA]     = 0x3F80;
    pfB[(size_t)b * KP + PF + NBETA + 1] = 0x3F80;
    for (int k = PF + NBETA + 2; k < KP; ++k) pfB[(size_t)b * KP + k] = 0;
}

// ---------------------------------------------------------------------------
// k_main v7: ks-outer register GEMM1 (A-frags loaded ONCE) + R8-style LDS
// round-trip so the epilogue keeps the measured-clean store pattern.
// mfma(A=pdT, B=pfB) -> D row=vert, col=batch -> xls[batch][c*16+vert] (b128).
// GEMM2 -> per-wave Tls[vert][be] bf16. Barrier-free (wave-private LDS).
// Epilogue lane: vertex = w*16+lr, batches hi2+4q. 1-D grid, XCD-bijective
// swizzle so each XCD sees ~1/8 of the vt (pdT) slices.
// ---------------------------------------------------------------------------
__global__ __launch_bounds__(256, 4) void k_main(
    const unsigned short* __restrict__ pdT,    // (3*VPAD, KP) c-major
    const unsigned short* __restrict__ pfB,    // (BB, KP)
    const unsigned short* __restrict__ lbswB,  // (VPAD, K2)
    const unsigned short* __restrict__ relBT,  // (BB*12, K2)
    float* __restrict__ verts)                 // (B,V,3)
{
    int bid = blockIdx.x;                       // 0..1727
    int wg  = (bid & 7) * (NWG / 8) + (bid >> 3);   // XCD-bijective swizzle
    int vt  = wg >> 4;          // 0..107
    int btg = wg & 15;          // 0..15
    int t   = threadIdx.x;
    int lane = t & 63;
    int w    = t >> 6;

    __shared__ float xls[4][16 * XSW];            // 13312 B
    __shared__ unsigned short Tls[4][16 * TSW];   // 25344 B

    int lr  = lane & 15;
    int hi2 = lane >> 4;
    int lk  = hi2 * 8;
    int v0w = vt * VTB + w * 16;

    float* xw = &xls[w][0];
    unsigned short* Tw = &Tls[w][0];

    const unsigned short* pa  = pdT + (size_t)(v0w + lr) * KP + lk;      // A: row=vert
    const unsigned short* pb0 = pfB + (size_t)(btg * 64 + lr) * KP + lk; // B: row=batch
    s16x8 lf = *(const s16x8*)(lbswB + (size_t)(v0w + lr) * K2 + lk);

    // ---- GEMM1, ks-outer: acc[it][c] -> D row=vert(hi2*4+r), col=batch(lr)
    f32x4 acc[NBT][3];
#pragma unroll
    for (int it = 0; it < NBT; ++it)
#pragma unroll
        for (int c = 0; c < 3; ++c) acc[it][c] = (f32x4){0.f,0.f,0.f,0.f};

#pragma unroll
    for (int ks = 0; ks < KP / 32; ++ks) {
        s16x8 a0 = *(const s16x8*)(pa + ks * 32);
        s16x8 a1 = *(const s16x8*)(pa + (size_t)VPAD * KP + ks * 32);
        s16x8 a2 = *(const s16x8*)(pa + (size_t)2 * VPAD * KP + ks * 32);
#pragma unroll
        for (int it = 0; it < NBT; ++it) {
            s16x8 bf = *(const s16x8*)(pb0 + (size_t)(it * 16) * KP + ks * 32);
            acc[it][0] = __builtin_amdgcn_mfma_f32_16x16x32_bf16(a0, bf, acc[it][0], 0, 0, 0);
            acc[it][1] = __builtin_amdgcn_mfma_f32_16x16x32_bf16(a1, bf, acc[it][1], 0, 0, 0);
            acc[it][2] = __builtin_amdgcn_mfma_f32_16x16x32_bf16(a2, bf, acc[it][2], 0, 0, 0);
        }
    }

    int vglob = v0w + lr;
    bool vok = vglob < VV;

#pragma unroll
    for (int it = 0; it < NBT; ++it) {
        int bt16 = btg * 64 + it * 16;

        // ---- xls: [batch=lr][c*16 + vert(hi2*4+r)], b128 writes ----
#pragma unroll
        for (int c = 0; c < 3; ++c)
            *(f32x4*)&xw[lr * XSW + c * 16 + hi2 * 4] = acc[it][c];

        // ---- GEMM2: T[be][vert] -> Tw[vert=lr][be] (per-wave) ----
#pragma unroll
        for (int mt = 0; mt < 12; ++mt) {
            s16x8 rf = *(const s16x8*)(relBT +
                (size_t)(bt16 * 12 + mt * 16 + lr) * K2 + lk);
            f32x4 a2v = {0.f,0.f,0.f,0.f};
            a2v = __builtin_amdgcn_mfma_f32_16x16x32_bf16(rf, lf, a2v, 0, 0, 0);
            union { s16x4 v4; unsigned short u[4]; } pk;
#pragma unroll
            for (int r = 0; r < 4; ++r) pk.u[r] = f2bf(a2v[r]);
            *(s16x4*)&Tw[lr * TSW + mt * 16 + hi2 * 4] = pk.v4;
        }

        // ---- epilogue: vertex w*16+lr, batches hi2+4q (R8 pattern) ----
        if (vok) {
#pragma unroll
            for (int q = 0; q < 4; ++q) {
                int bl = hi2 + 4 * q;

                float x0 = xw[bl * XSW + 0 * 16 + lr];
                float x1 = xw[bl * XSW + 1 * 16 + lr];
                float x2 = xw[bl * XSW + 2 * 16 + lr];

                const unsigned short* tp = Tw + lr * TSW + bl * 12;
                uint2 dA = *(const uint2*)tp;
                uint2 dB = *(const uint2*)(tp + 4);
                uint2 dC = *(const uint2*)(tp + 8);
                float T0  = __uint_as_float(dA.x << 16);
                float T1  = __uint_as_float(dA.x & 0xffff0000u);
                float T2  = __uint_as_float(dA.y << 16);
                float T3  = __uint_as_float(dA.y & 0xffff0000u);
                float T4  = __uint_as_float(dB.x << 16);
                float T5  = __uint_as_float(dB.x & 0xffff0000u);
                float T6  = __uint_as_float(dB.y << 16);
                float T7  = __uint_as_float(dB.y & 0xffff0000u);
                float T8  = __uint_as_float(dC.x << 16);
                float T9  = __uint_as_float(dC.x & 0xffff0000u);
                float T10 = __uint_as_float(dC.y << 16);
                float T11 = __uint_as_float(dC.y & 0xffff0000u);

                float o0 = T0 * x0 + T1 * x1 + T2  * x2 + T3;
                float o1 = T4 * x0 + T5 * x1 + T6  * x2 + T7;
                float o2 = T8 * x0 + T9 * x1 + T10 * x2 + T11;

                float* o = verts + ((size_t)(bt16 + bl) * VV + vglob) * 3;
                o[0] = o0; o[1] = o1; o[2] = o2;
            }
        }
    }
}

extern "C" void kernel_launch(void* const* d_in, const int* in_sizes, int n_in,
                              void* d_out, int out_size, void* d_ws, size_t ws_size,
                              hipStream_t stream) {
    const float* transl = (const float*)d_in[0];
    const float* orient = (const float*)d_in[1];
    const float* betas  = (const float*)d_in[2];
    const float* bpose  = (const float*)d_in[3];
    const float* vtemp  = (const float*)d_in[4];
    const float* sdirs  = (const float*)d_in[5];
    const float* pdirs  = (const float*)d_in[6];
    const float* jreg   = (const float*)d_in[7];
    const float* lbsw   = (const float*)d_in[8];

    float* out = (float*)d_out;
    float* verts_out  = out;
    float* joints_out = out + (size_t)BB * VV * 3;

    float* ws    = (float*)d_ws;
    float* jpart = ws;                                   // 24*24*33 = 19008 f
    float* sJg   = ws + 19008;                           // 792 f
    unsigned short* pfB   = (unsigned short*)(ws + 19008 + 792); // B*KP
    unsigned short* pdT   = pfB + (size_t)BB * KP;             // 3*VPAD*KP
    unsigned short* lbswB = pdT + (size_t)3 * VPAD * KP;       // VPAD*K2
    unsigned short* relBT = lbswB + (size_t)VPAD * K2;         // B*12*K2

    k_prep_all<<<NBLK_A + NBLK_B + NBLK_C, 256, 0, stream>>>(
        pdirs, sdirs, vtemp, lbsw, jreg, pdT, lbswB, jpart);
    k_jred<<<1, 256, 0, stream>>>(jpart, sJg);
    k_batch<<<BB / 32, 32, 0, stream>>>(transl, orient, betas, bpose,
                                        sJg, pfB, relBT, joints_out);
    k_main<<<NWG, 256, 0, stream>>>(pdT, pfB, lbswB, relBT, verts_out);
}

// Round 12
// 150.304 us; speedup vs baseline: 1.6264x; 1.6264x over previous
//
#include <hip/hip_runtime.h>

#define BB 1024
#define VV 6890
#define NJ 24
#define NBETA 10
#define PF 207            // (J-1)*9
#define V3 (VV*3)         // 20670
#define KP 224            // GEMM1 K: 207 pose + 10 shape + 2 vtemp(hi/lo) + 5 zero
#define VTB 64            // vertices per block tile in k_main
#define NVT ((VV + VTB - 1) / VTB)   // 108
#define VPAD (NVT * VTB)             // 6912 rows per component in pdT
#define K2 32             // GEMM2 K: 24 joints + 1 transl-one + 7 zero
#define NCH 8             // jreg chunks
#define CHV 862           // ceil(VV/NCH)
#define NBLK_A (NVT * 4)             // 432: (v-block, k-quarter)
#define NBLK_B (VPAD / 256)          // 27
#define NBLK_C (NJ * NCH)            // 192
#define NBT 4             // batch-tiles per k_main block
#define XSW 52            // xls per-wave stride (dwords): [batch][c*16+vert]
#define TSW 198           // Tls per-wave stride (u16):   [vert][be]

typedef float f32x4 __attribute__((ext_vector_type(4)));
typedef short s16x8 __attribute__((ext_vector_type(8)));
typedef short s16x4 __attribute__((ext_vector_type(4)));

__device__ __constant__ int kParents[NJ] = {-1,0,0,0,1,2,3,4,5,6,7,8,9,9,9,12,13,14,16,17,18,19,20,21};

__device__ __forceinline__ unsigned short f2bf(float x) {
    unsigned int u = __float_as_uint(x);
    unsigned int r = (u + 0x7fffu + ((u >> 16) & 1u)) >> 16;
    return (unsigned short)r;
}
__device__ __forceinline__ float bf2f(unsigned short h) {
    return __uint_as_float((unsigned int)h << 16);
}

// ---------------------------------------------------------------------------
// k_prep_all: 3 block-ranges:
//  A [0,432):    pdT rows, COMPONENT-MAJOR (row = c*VPAD+v), 4-way k-split,
//                LDS-staged transpose (coalesced loads, 16B stores).
//  B [432,459):  lbswB rows — GEMM2 operand (w(24) | 1.0 | 0(7))
//  C [459,651):  jreg partials (24 joints x 8 chunks, fully parallel)
// ---------------------------------------------------------------------------
__global__ __launch_bounds__(256) void k_prep_all(
    const float* __restrict__ pdirs,     // (207, V3)
    const float* __restrict__ sdirs,     // (V3, 10)
    const float* __restrict__ vtemp,     // (V3)
    const float* __restrict__ lbsw,      // (V, 24)
    const float* __restrict__ Jreg,      // (24, V)
    unsigned short* __restrict__ pdT,    // (3*VPAD, KP) component-major
    unsigned short* __restrict__ lbswB,  // (VPAD, K2)
    float* __restrict__ jpart)           // (24, NCH, 33)
{
    int bid = blockIdx.x;
    int t = threadIdx.x;

    if (bid < NBLK_A) {
        int vb = bid >> 2;              // v-block 0..107
        int kq = bid & 3;               // k-quarter 0..3
        int kc0 = kq * 56;
        int v0 = vb * 64;
        __shared__ unsigned short tileA[3][56][65];   // 21840 B

        int ksub = t >> 6;              // 0..3
        int vo   = t & 63;
        int v    = v0 + vo;
        bool valid = v < VV;
        int v3b  = v * 3;
#pragma unroll
        for (int i = 0; i < 14; ++i) {
            int kl = ksub * 14 + i;     // 0..55
            int k  = kc0 + kl;
            float c0 = 0.f, c1 = 0.f, c2 = 0.f;
            if (valid) {
                if (k < PF) {
                    const float* p = pdirs + (size_t)k * V3 + v3b;
                    c0 = p[0]; c1 = p[1]; c2 = p[2];
                } else if (k < PF + NBETA) {
                    int l = k - PF;
                    c0 = sdirs[(size_t)(v3b + 0) * NBETA + l];
                    c1 = sdirs[(size_t)(v3b + 1) * NBETA + l];
                    c2 = sdirs[(size_t)(v3b + 2) * NBETA + l];
                } else if (k == PF + NBETA) {
                    c0 = vtemp[v3b]; c1 = vtemp[v3b + 1]; c2 = vtemp[v3b + 2];
                } else if (k == PF + NBETA + 1) {
                    float x0 = vtemp[v3b], x1 = vtemp[v3b + 1], x2 = vtemp[v3b + 2];
                    c0 = x0 - bf2f(f2bf(x0));
                    c1 = x1 - bf2f(f2bf(x1));
                    c2 = x2 - bf2f(f2bf(x2));
                }
            }
            tileA[0][kl][vo] = f2bf(c0);
            tileA[1][kl][vo] = f2bf(c1);
            tileA[2][kl][vo] = f2bf(c2);
        }
        __syncthreads();

        int vo2 = t >> 2;               // 0..63
        int sub = t & 3;
#pragma unroll
        for (int c = 0; c < 3; ++c) {
#pragma unroll
            for (int j = 0; j < 2; ++j) {
                int ch = sub + 4 * j;   // 0..7, need 0..6 (7 chunks x 8 = 56)
                if (ch < 7) {
                    union { s16x8 v8; unsigned short u[8]; } pk;
#pragma unroll
                    for (int i = 0; i < 8; ++i) pk.u[i] = tileA[c][ch * 8 + i][vo2];
                    *(s16x8*)(pdT + (size_t)(c * VPAD + v0 + vo2) * KP
                                   + kc0 + ch * 8) = pk.v8;
                }
            }
        }
    } else if (bid < NBLK_A + NBLK_B) {
        int v = (bid - NBLK_A) * 256 + t;
        bool valid = v < VV;
        unsigned short* o = lbswB + (size_t)v * K2;
        union { s16x8 v8; unsigned short u[8]; } pk;
#pragma unroll
        for (int g = 0; g < 3; ++g) {
#pragma unroll
            for (int i = 0; i < 8; ++i)
                pk.u[i] = valid ? f2bf(lbsw[(size_t)v * NJ + g * 8 + i]) : (unsigned short)0;
            *(s16x8*)(o + g * 8) = pk.v8;
        }
        pk.u[0] = 0x3F80;               // col 24 = 1.0 (transl K-column)
#pragma unroll
        for (int i = 1; i < 8; ++i) pk.u[i] = 0;
        *(s16x8*)(o + 24) = pk.v8;
    } else {
        int idx = bid - NBLK_A - NBLK_B;
        int j  = idx / NCH;
        int ch = idx % NCH;
        int v0 = ch * CHV;
        int vend = min(VV, v0 + CHV);

        float acc[33];
#pragma unroll
        for (int i = 0; i < 33; ++i) acc[i] = 0.f;

        for (int v = v0 + t; v < vend; v += 256) {
            float w = Jreg[(size_t)j * VV + v];
#pragma unroll
            for (int c = 0; c < 3; ++c) {
                acc[30 + c] += w * vtemp[v * 3 + c];
#pragma unroll
                for (int l = 0; l < NBETA; ++l)
                    acc[c * NBETA + l] += w * sdirs[(size_t)(v * 3 + c) * NBETA + l];
            }
        }
#pragma unroll
        for (int i = 0; i < 33; ++i) {
            float x = acc[i];
            for (int off = 32; off > 0; off >>= 1) x += __shfl_down(x, off);
            acc[i] = x;
        }
        __shared__ float sred[33][4];
        int wave = t >> 6, lane = t & 63;
        if (lane == 0) {
#pragma unroll
            for (int i = 0; i < 33; ++i) sred[i][wave] = acc[i];
        }
        __syncthreads();
        if (t == 0) {
#pragma unroll
            for (int i = 0; i < 33; ++i)
                jpart[(size_t)(j * NCH + ch) * 33 + i] =
                    sred[i][0] + sred[i][1] + sred[i][2] + sred[i][3];
        }
    }
}

// ---------------------------------------------------------------------------
// k_jred: reduce jpart (24, NCH, 33) -> sJg (24*33)
// ---------------------------------------------------------------------------
__global__ __launch_bounds__(256) void k_jred(
    const float* __restrict__ jpart,
    float* __restrict__ sJg)             // (NJ*33)
{
    for (int idx = threadIdx.x; idx < NJ * 33; idx += 256) {
        int j = idx / 33, i = idx % 33;
        float s = 0.f;
#pragma unroll
        for (int c = 0; c < NCH; ++c) s += jpart[(size_t)(j * NCH + c) * 33 + i];
        sJg[j * 33 + i] = s;
    }
}

// ---------------------------------------------------------------------------
// k_batch: rodrigues, kinematic chain, pose features -> pfB,
// rel transforms (+transl in col 24) -> relBT, posed joints -> out.
// ---------------------------------------------------------------------------
__global__ __launch_bounds__(32) void k_batch(
    const float* __restrict__ transl,
    const float* __restrict__ orient,
    const float* __restrict__ betas,
    const float* __restrict__ bpose,
    const float* __restrict__ sJg,       // (NJ*33)
    unsigned short* __restrict__ pfB,    // (B, KP)
    unsigned short* __restrict__ relBT,  // (B*12, K2)
    float* __restrict__ joints_out)      // (B, 24, 3)
{
    int t = threadIdx.x;
    int b = blockIdx.x * 32 + t;

    __shared__ float sJ[NJ * 33];
    __shared__ float chain[NJ][12][32];

    for (int idx = t; idx < NJ * 33; idx += 32) sJ[idx] = sJg[idx];
    __syncthreads();

    float bet[NBETA];
#pragma unroll
    for (int l = 0; l < NBETA; ++l) bet[l] = betas[b * NBETA + l];

    float jx[NJ], jy[NJ], jz[NJ];
#pragma unroll
    for (int j = 0; j < NJ; ++j) {
        float a = sJ[j * 33 + 30], bb = sJ[j * 33 + 31], cc = sJ[j * 33 + 32];
#pragma unroll
        for (int l = 0; l < NBETA; ++l) {
            a  += sJ[j * 33 + l]      * bet[l];
            bb += sJ[j * 33 + 10 + l] * bet[l];
            cc += sJ[j * 33 + 20 + l] * bet[l];
        }
        jx[j] = a; jy[j] = bb; jz[j] = cc;
    }

    float tr0 = transl[b * 3 + 0], tr1 = transl[b * 3 + 1], tr2 = transl[b * 3 + 2];

    for (int j = 0; j < NJ; ++j) {
        float rx, ry, rz;
        if (j == 0) {
            rx = orient[b * 3 + 0]; ry = orient[b * 3 + 1]; rz = orient[b * 3 + 2];
        } else {
            rx = bpose[b * 69 + (j - 1) * 3 + 0];
            ry = bpose[b * 69 + (j - 1) * 3 + 1];
            rz = bpose[b * 69 + (j - 1) * 3 + 2];
        }
        float ax = rx + 1e-8f, ay = ry + 1e-8f, az = rz + 1e-8f;
        float angle = sqrtf(ax * ax + ay * ay + az * az);
        float inv = 1.f / angle;
        float kx = rx * inv, ky = ry * inv, kz = rz * inv;
        float s = sinf(angle), c = cosf(angle), omc = 1.f - c;
        float R[9];
        R[0] = 1.f - omc * (ky * ky + kz * kz);
        R[1] = -s * kz + omc * (kx * ky);
        R[2] =  s * ky + omc * (kx * kz);
        R[3] =  s * kz + omc * (kx * ky);
        R[4] = 1.f - omc * (kx * kx + kz * kz);
        R[5] = -s * kx + omc * (ky * kz);
        R[6] = -s * ky + omc * (kx * kz);
        R[7] =  s * kx + omc * (ky * kz);
        R[8] = 1.f - omc * (kx * kx + ky * ky);

        if (j > 0) {
#pragma unroll
            for (int e = 0; e < 9; ++e) {
                float val = R[e] - ((e == 0 || e == 4 || e == 8) ? 1.f : 0.f);
                pfB[(size_t)b * KP + (j - 1) * 9 + e] = f2bf(val);
            }
        }

        int p = kParents[j];
        float tx, ty, tz;
        if (j == 0) { tx = jx[0]; ty = jy[0]; tz = jz[0]; }
        else        { tx = jx[j] - jx[p]; ty = jy[j] - jy[p]; tz = jz[j] - jz[p]; }

        float A[12];
        if (j == 0) {
            A[0] = R[0]; A[1] = R[1]; A[2]  = R[2]; A[3]  = tx;
            A[4] = R[3]; A[5] = R[4]; A[6]  = R[5]; A[7]  = ty;
            A[8] = R[6]; A[9] = R[7]; A[10] = R[8]; A[11] = tz;
        } else {
            float P[12];
#pragma unroll
            for (int e = 0; e < 12; ++e) P[e] = chain[p][e][t];
#pragma unroll
            for (int r = 0; r < 3; ++r) {
#pragma unroll
                for (int cc = 0; cc < 3; ++cc)
                    A[r * 4 + cc] = P[r * 4 + 0] * R[0 * 3 + cc] +
                                    P[r * 4 + 1] * R[1 * 3 + cc] +
                                    P[r * 4 + 2] * R[2 * 3 + cc];
                A[r * 4 + 3] = P[r * 4 + 0] * tx + P[r * 4 + 1] * ty +
                               P[r * 4 + 2] * tz + P[r * 4 + 3];
            }
        }
#pragma unroll
        for (int e = 0; e < 12; ++e) chain[j][e][t] = A[e];

        joints_out[(b * NJ + j) * 3 + 0] = A[3]  + tr0;
        joints_out[(b * NJ + j) * 3 + 1] = A[7]  + tr1;
        joints_out[(b * NJ + j) * 3 + 2] = A[11] + tr2;

        float bx = A[0] * jx[j] + A[1] * jy[j] + A[2]  * jz[j];
        float by = A[4] * jx[j] + A[5] * jy[j] + A[6]  * jz[j];
        float bz = A[8] * jx[j] + A[9] * jy[j] + A[10] * jz[j];
        float relv[12];
        relv[0] = A[0]; relv[1] = A[1]; relv[2]  = A[2];  relv[3]  = A[3]  - bx;
        relv[4] = A[4]; relv[5] = A[5]; relv[6]  = A[6];  relv[7]  = A[7]  - by;
        relv[8] = A[8]; relv[9] = A[9]; relv[10] = A[10]; relv[11] = A[11] - bz;
#pragma unroll
        for (int e = 0; e < 12; ++e)
            relBT[(size_t)(b * 12 + e) * K2 + j] = f2bf(relv[e]);
    }

    // relBT tail: col 24 = transl component (paired with lbswB col24 = 1.0)
#pragma unroll
    for (int e = 0; e < 12; ++e) {
        float tv = (e == 3) ? tr0 : (e == 7) ? tr1 : (e == 11) ? tr2 : 0.f;
        relBT[(size_t)(b * 12 + e) * K2 + 24] = f2bf(tv);
#pragma unroll
        for (int j2 = NJ + 1; j2 < K2; ++j2)
            relBT[(size_t)(b * 12 + e) * K2 + j2] = 0;
    }

    // pfB tail: betas, ones (vtemp hi/lo), zero pad to KP
#pragma unroll
    for (int l = 0; l < NBETA; ++l)
        pfB[(size_t)b * KP + PF + l] = f2bf(bet[l]);
    pfB[(size_t)b * KP + PF + NBETA]     = 0x3F80;
    pfB[(size_t)b * KP + PF + NBETA + 1] = 0x3F80;
    for (int k = PF + NBETA + 2; k < KP; ++k) pfB[(size_t)b * KP + k] = 0;
}

// ---------------------------------------------------------------------------
// k_main v8 = R8's proven structure (per-batch-tile GEMM1, barrier-free,
// wave-private LDS, 2-D grid) + b128 conflict-free xls writes:
//   xls layout [batch(lr)][c*16+vert] stride 52 -> 3x ds_write_b128/it,
//   uniform bank histogram (8 touches/bank = minimum).
// GEMM1: mfma(A=pdT c-major row=vert, B=pfB row=batch) per batch-tile.
// GEMM2: mfma(A=relBT, B=lbswB) -> Tls[vert][be] bf16 (measured 0-conflict).
// Epilogue lane: vertex = w*16+lr, batches hi2+4q (measured-clean stores).
// ---------------------------------------------------------------------------
__global__ __launch_bounds__(256, 4) void k_main(
    const unsigned short* __restrict__ pdT,    // (3*VPAD, KP) c-major
    const unsigned short* __restrict__ pfB,    // (BB, KP)
    const unsigned short* __restrict__ lbswB,  // (VPAD, K2)
    const unsigned short* __restrict__ relBT,  // (BB*12, K2)
    float* __restrict__ verts)                 // (B,V,3)
{
    int btg = blockIdx.x;           // 0..15 (4 batch-tiles each)
    int vt  = blockIdx.y;           // 0..107
    int t   = threadIdx.x;
    int lane = t & 63;
    int w    = t >> 6;

    __shared__ float xls[4][16 * XSW];            // 13312 B
    __shared__ unsigned short Tls[4][16 * TSW];   // 25344 B

    int lr  = lane & 15;
    int hi2 = lane >> 4;
    int lk  = hi2 * 8;
    int v0w = vt * VTB + w * 16;

    float* xw = &xls[w][0];
    unsigned short* Tw = &Tls[w][0];

    const unsigned short* pa = pdT + (size_t)(v0w + lr) * KP + lk;   // A: row=vert
    s16x8 lf = *(const s16x8*)(lbswB + (size_t)(v0w + lr) * K2 + lk);

    int vglob = v0w + lr;
    bool vok = vglob < VV;

    for (int it = 0; it < NBT; ++it) {
        int bt16 = btg * 64 + it * 16;

        // ---- GEMM1 (per batch-tile): D row=vert(hi2*4+r), col=batch(lr) ----
        {
            f32x4 acc[3];
#pragma unroll
            for (int c = 0; c < 3; ++c) acc[c] = (f32x4){0.f,0.f,0.f,0.f};
            const unsigned short* pb = pfB + (size_t)(bt16 + lr) * KP + lk;
#pragma unroll
            for (int ks = 0; ks < KP / 32; ++ks) {
                s16x8 bf = *(const s16x8*)(pb + ks * 32);
                s16x8 a0 = *(const s16x8*)(pa + ks * 32);
                s16x8 a1 = *(const s16x8*)(pa + (size_t)VPAD * KP + ks * 32);
                s16x8 a2 = *(const s16x8*)(pa + (size_t)2 * VPAD * KP + ks * 32);
                acc[0] = __builtin_amdgcn_mfma_f32_16x16x32_bf16(a0, bf, acc[0], 0, 0, 0);
                acc[1] = __builtin_amdgcn_mfma_f32_16x16x32_bf16(a1, bf, acc[1], 0, 0, 0);
                acc[2] = __builtin_amdgcn_mfma_f32_16x16x32_bf16(a2, bf, acc[2], 0, 0, 0);
            }
            // b128 writes: xw[batch=lr][c*16 + vert(hi2*4+r)], r contiguous
#pragma unroll
            for (int c = 0; c < 3; ++c)
                *(f32x4*)&xw[lr * XSW + c * 16 + hi2 * 4] = acc[c];
        }

        // ---- GEMM2: T[be][vert] -> Tw[vert=lr][be] (per-wave) ----
#pragma unroll
        for (int mt = 0; mt < 12; ++mt) {
            s16x8 rf = *(const s16x8*)(relBT +
                (size_t)(bt16 * 12 + mt * 16 + lr) * K2 + lk);
            f32x4 a2v = {0.f,0.f,0.f,0.f};
            a2v = __builtin_amdgcn_mfma_f32_16x16x32_bf16(rf, lf, a2v, 0, 0, 0);
            union { s16x4 v4; unsigned short u[4]; } pk;
#pragma unroll
            for (int r = 0; r < 4; ++r) pk.u[r] = f2bf(a2v[r]);
            *(s16x4*)&Tw[lr * TSW + mt * 16 + hi2 * 4] = pk.v4;
        }

        // ---- epilogue: vertex w*16+lr, batches hi2+4q ----
        if (vok) {
#pragma unroll
            for (int q = 0; q < 4; ++q) {
                int bl = hi2 + 4 * q;

                float x0 = xw[bl * XSW + 0 * 16 + lr];
                float x1 = xw[bl * XSW + 1 * 16 + lr];
                float x2 = xw[bl * XSW + 2 * 16 + lr];

                const unsigned short* tp = Tw + lr * TSW + bl * 12;
                uint2 dA = *(const uint2*)tp;
                uint2 dB = *(const uint2*)(tp + 4);
                uint2 dC = *(const uint2*)(tp + 8);
                float T0  = __uint_as_float(dA.x << 16);
                float T1  = __uint_as_float(dA.x & 0xffff0000u);
                float T2  = __uint_as_float(dA.y << 16);
                float T3  = __uint_as_float(dA.y & 0xffff0000u);
                float T4  = __uint_as_float(dB.x << 16);
                float T5  = __uint_as_float(dB.x & 0xffff0000u);
                float T6  = __uint_as_float(dB.y << 16);
                float T7  = __uint_as_float(dB.y & 0xffff0000u);
                float T8  = __uint_as_float(dC.x << 16);
                float T9  = __uint_as_float(dC.x & 0xffff0000u);
                float T10 = __uint_as_float(dC.y << 16);
                float T11 = __uint_as_float(dC.y & 0xffff0000u);

                float o0 = T0 * x0 + T1 * x1 + T2  * x2 + T3;
                float o1 = T4 * x0 + T5 * x1 + T6  * x2 + T7;
                float o2 = T8 * x0 + T9 * x1 + T10 * x2 + T11;

                float* o = verts + ((size_t)(bt16 + bl) * VV + vglob) * 3;
                o[0] = o0; o[1] = o1; o[2] = o2;
            }
        }
    }
}

extern "C" void kernel_launch(void* const* d_in, const int* in_sizes, int n_in,
                              void* d_out, int out_size, void* d_ws, size_t ws_size,
                              hipStream_t stream) {
    const float* transl = (const float*)d_in[0];
    const float* orient = (const float*)d_in[1];
    const float* betas  = (const float*)d_in[2];
    const float* bpose  = (const float*)d_in[3];
    const float* vtemp  = (const float*)d_in[4];
    const float* sdirs  = (const float*)d_in[5];
    const float* pdirs  = (const float*)d_in[6];
    const float* jreg   = (const float*)d_in[7];
    const float* lbsw   = (const float*)d_in[8];

    float* out = (float*)d_out;
    float* verts_out  = out;
    float* joints_out = out + (size_t)BB * VV * 3;

    float* ws    = (float*)d_ws;
    float* jpart = ws;                                   // 24*8*33 = 6336 f
    float* sJg   = ws + 6336;                            // 792 f
    unsigned short* pfB   = (unsigned short*)(ws + 6336 + 792); // B*KP
    unsigned short* pdT   = pfB + (size_t)BB * KP;             // 3*VPAD*KP
    unsigned short* lbswB = pdT + (size_t)3 * VPAD * KP;       // VPAD*K2
    unsigned short* relBT = lbswB + (size_t)VPAD * K2;         // B*12*K2

    k_prep_all<<<NBLK_A + NBLK_B + NBLK_C, 256, 0, stream>>>(
        pdirs, sdirs, vtemp, lbsw, jreg, pdT, lbswB, jpart);
    k_jred<<<1, 256, 0, stream>>>(jpart, sJg);
    k_batch<<<BB / 32, 32, 0, stream>>>(transl, orient, betas, bpose,
                                        sJg, pfB, relBT, joints_out);
    dim3 g(BB / 16 / NBT, NVT);
    k_main<<<g, 256, 0, stream>>>(pdT, pfB, lbswB, relBT, verts_out);
}

// Round 13
// 117.648 us; speedup vs baseline: 2.0779x; 1.2776x over previous
//
#include <hip/hip_runtime.h>

#define BB 1024
#define VV 6890
#define NJ 24
#define NBETA 10
#define PF 207            // (J-1)*9
#define V3 (VV*3)         // 20670
#define KP 224            // GEMM1 K: 207 pose + 10 shape + 2 vtemp(hi/lo) + 5 zero
#define VTB 64            // vertices per block tile in k_main
#define M3 (VTB*3)        // 192 v3-rows per tile
#define NVT ((VV + VTB - 1) / VTB)   // 108
#define V3PAD (NVT * VTB * 3)        // 20736 rows in pdT (row = v*3+c, interleaved)
#define VPAD (NVT * VTB)             // 6912
#define K2 32             // GEMM2 K: 24 joints + 1 transl-one + 7 zero
#define NCH 8             // jreg chunks
#define CHV 862           // ceil(VV/NCH)
#define NBLK_A (NVT * 4)             // 432: (v-block, k-quarter)
#define NBLK_B (VPAD / 256)          // 27
#define NBLK_C (NJ * NCH)            // 192
#define NBT 4             // batch-tiles per k_main block
#define XSW 52            // xls per-wave stride (dwords): [batch][v3local]
#define TSW 200           // Tls per-wave stride (u16): 400B, 8-B aligned for all lr

typedef float f32x4 __attribute__((ext_vector_type(4)));
typedef short s16x8 __attribute__((ext_vector_type(8)));
typedef short s16x4 __attribute__((ext_vector_type(4)));

__device__ __constant__ int kParents[NJ] = {-1,0,0,0,1,2,3,4,5,6,7,8,9,9,9,12,13,14,16,17,18,19,20,21};

__device__ __forceinline__ unsigned short f2bf(float x) {
    unsigned int u = __float_as_uint(x);
    unsigned int r = (u + 0x7fffu + ((u >> 16) & 1u)) >> 16;
    return (unsigned short)r;
}
__device__ __forceinline__ float bf2f(unsigned short h) {
    return __uint_as_float((unsigned int)h << 16);
}

// ---------------------------------------------------------------------------
// k_prep_all: 3 block-ranges:
//  A [0,432):    pdT rows INTERLEAVED (row = v*3+c) — R8's measured-best
//                layout — via LDS-staged transpose (coalesced loads).
//  B [432,459):  lbswB rows — GEMM2 operand (w(24) | 1.0 | 0(7))
//  C [459,651):  jreg partials (24 joints x 8 chunks, fully parallel)
// ---------------------------------------------------------------------------
__global__ __launch_bounds__(256) void k_prep_all(
    const float* __restrict__ pdirs,     // (207, V3)
    const float* __restrict__ sdirs,     // (V3, 10)
    const float* __restrict__ vtemp,     // (V3)
    const float* __restrict__ lbsw,      // (V, 24)
    const float* __restrict__ Jreg,      // (24, V)
    unsigned short* __restrict__ pdT,    // (V3PAD, KP) interleaved
    unsigned short* __restrict__ lbswB,  // (VPAD, K2)
    float* __restrict__ jpart)           // (24, NCH, 33)
{
    int bid = blockIdx.x;
    int t = threadIdx.x;

    if (bid < NBLK_A) {
        int vb = bid >> 2;              // v-block 0..107
        int kq = bid & 3;               // k-quarter 0..3
        int kc0 = kq * 56;
        int v0 = vb * 64;
        __shared__ unsigned short tileA[3][56][65];   // 21840 B

        int ksub = t >> 6;              // 0..3
        int vo   = t & 63;
        int v    = v0 + vo;
        bool valid = v < VV;
        int v3b  = v * 3;
#pragma unroll
        for (int i = 0; i < 14; ++i) {
            int kl = ksub * 14 + i;     // 0..55
            int k  = kc0 + kl;
            float c0 = 0.f, c1 = 0.f, c2 = 0.f;
            if (valid) {
                if (k < PF) {
                    const float* p = pdirs + (size_t)k * V3 + v3b;
                    c0 = p[0]; c1 = p[1]; c2 = p[2];
                } else if (k < PF + NBETA) {
                    int l = k - PF;
                    c0 = sdirs[(size_t)(v3b + 0) * NBETA + l];
                    c1 = sdirs[(size_t)(v3b + 1) * NBETA + l];
                    c2 = sdirs[(size_t)(v3b + 2) * NBETA + l];
                } else if (k == PF + NBETA) {
                    c0 = vtemp[v3b]; c1 = vtemp[v3b + 1]; c2 = vtemp[v3b + 2];
                } else if (k == PF + NBETA + 1) {
                    float x0 = vtemp[v3b], x1 = vtemp[v3b + 1], x2 = vtemp[v3b + 2];
                    c0 = x0 - bf2f(f2bf(x0));
                    c1 = x1 - bf2f(f2bf(x1));
                    c2 = x2 - bf2f(f2bf(x2));
                }
            }
            tileA[0][kl][vo] = f2bf(c0);
            tileA[1][kl][vo] = f2bf(c1);
            tileA[2][kl][vo] = f2bf(c2);
        }
        __syncthreads();

        int vo2 = t >> 2;               // 0..63
        int sub = t & 3;
#pragma unroll
        for (int c = 0; c < 3; ++c) {
#pragma unroll
            for (int j = 0; j < 2; ++j) {
                int ch = sub + 4 * j;   // 0..7, need 0..6 (7 chunks x 8 = 56)
                if (ch < 7) {
                    union { s16x8 v8; unsigned short u[8]; } pk;
#pragma unroll
                    for (int i = 0; i < 8; ++i) pk.u[i] = tileA[c][ch * 8 + i][vo2];
                    *(s16x8*)(pdT + (size_t)((v0 + vo2) * 3 + c) * KP
                                   + kc0 + ch * 8) = pk.v8;
                }
            }
        }
    } else if (bid < NBLK_A + NBLK_B) {
        int v = (bid - NBLK_A) * 256 + t;
        bool valid = v < VV;
        unsigned short* o = lbswB + (size_t)v * K2;
        union { s16x8 v8; unsigned short u[8]; } pk;
#pragma unroll
        for (int g = 0; g < 3; ++g) {
#pragma unroll
            for (int i = 0; i < 8; ++i)
                pk.u[i] = valid ? f2bf(lbsw[(size_t)v * NJ + g * 8 + i]) : (unsigned short)0;
            *(s16x8*)(o + g * 8) = pk.v8;
        }
        pk.u[0] = 0x3F80;               // col 24 = 1.0 (transl K-column)
#pragma unroll
        for (int i = 1; i < 8; ++i) pk.u[i] = 0;
        *(s16x8*)(o + 24) = pk.v8;
    } else {
        int idx = bid - NBLK_A - NBLK_B;
        int j  = idx / NCH;
        int ch = idx % NCH;
        int v0 = ch * CHV;
        int vend = min(VV, v0 + CHV);

        float acc[33];
#pragma unroll
        for (int i = 0; i < 33; ++i) acc[i] = 0.f;

        for (int v = v0 + t; v < vend; v += 256) {
            float w = Jreg[(size_t)j * VV + v];
#pragma unroll
            for (int c = 0; c < 3; ++c) {
                acc[30 + c] += w * vtemp[v * 3 + c];
#pragma unroll
                for (int l = 0; l < NBETA; ++l)
                    acc[c * NBETA + l] += w * sdirs[(size_t)(v * 3 + c) * NBETA + l];
            }
        }
#pragma unroll
        for (int i = 0; i < 33; ++i) {
            float x = acc[i];
            for (int off = 32; off > 0; off >>= 1) x += __shfl_down(x, off);
            acc[i] = x;
        }
        __shared__ float sred[33][4];
        int wave = t >> 6, lane = t & 63;
        if (lane == 0) {
#pragma unroll
            for (int i = 0; i < 33; ++i) sred[i][wave] = acc[i];
        }
        __syncthreads();
        if (t == 0) {
#pragma unroll
            for (int i = 0; i < 33; ++i)
                jpart[(size_t)(j * NCH + ch) * 33 + i] =
                    sred[i][0] + sred[i][1] + sred[i][2] + sred[i][3];
        }
    }
}

// ---------------------------------------------------------------------------
// k_batch: jpart reduce (preamble, R6-proven) -> rodrigues, kinematic chain,
// pose features -> pfB, rel transforms (+transl col 24) -> relBT, joints.
// ---------------------------------------------------------------------------
__global__ __launch_bounds__(32) void k_batch(
    const float* __restrict__ transl,
    const float* __restrict__ orient,
    const float* __restrict__ betas,
    const float* __restrict__ bpose,
    const float* __restrict__ jpart,     // (24, NCH, 33)
    unsigned short* __restrict__ pfB,    // (B, KP)
    unsigned short* __restrict__ relBT,  // (B*12, K2)
    float* __restrict__ joints_out)      // (B, 24, 3)
{
    int t = threadIdx.x;
    int b = blockIdx.x * 32 + t;

    __shared__ float sJ[NJ * 33];
    __shared__ float chain[NJ][12][32];

    for (int idx = t; idx < NJ * 33; idx += 32) {
        int j = idx / 33, i = idx % 33;
        float s = 0.f;
#pragma unroll
        for (int c = 0; c < NCH; ++c) s += jpart[(size_t)(j * NCH + c) * 33 + i];
        sJ[idx] = s;
    }
    __syncthreads();

    float bet[NBETA];
#pragma unroll
    for (int l = 0; l < NBETA; ++l) bet[l] = betas[b * NBETA + l];

    float jx[NJ], jy[NJ], jz[NJ];
#pragma unroll
    for (int j = 0; j < NJ; ++j) {
        float a = sJ[j * 33 + 30], bb = sJ[j * 33 + 31], cc = sJ[j * 33 + 32];
#pragma unroll
        for (int l = 0; l < NBETA; ++l) {
            a  += sJ[j * 33 + l]      * bet[l];
            bb += sJ[j * 33 + 10 + l] * bet[l];
            cc += sJ[j * 33 + 20 + l] * bet[l];
        }
        jx[j] = a; jy[j] = bb; jz[j] = cc;
    }

    float tr0 = transl[b * 3 + 0], tr1 = transl[b * 3 + 1], tr2 = transl[b * 3 + 2];

    for (int j = 0; j < NJ; ++j) {
        float rx, ry, rz;
        if (j == 0) {
            rx = orient[b * 3 + 0]; ry = orient[b * 3 + 1]; rz = orient[b * 3 + 2];
        } else {
            rx = bpose[b * 69 + (j - 1) * 3 + 0];
            ry = bpose[b * 69 + (j - 1) * 3 + 1];
            rz = bpose[b * 69 + (j - 1) * 3 + 2];
        }
        float ax = rx + 1e-8f, ay = ry + 1e-8f, az = rz + 1e-8f;
        float angle = sqrtf(ax * ax + ay * ay + az * az);
        float inv = 1.f / angle;
        float kx = rx * inv, ky = ry * inv, kz = rz * inv;
        float s = sinf(angle), c = cosf(angle), omc = 1.f - c;
        float R[9];
        R[0] = 1.f - omc * (ky * ky + kz * kz);
        R[1] = -s * kz + omc * (kx * ky);
        R[2] =  s * ky + omc * (kx * kz);
        R[3] =  s * kz + omc * (kx * ky);
        R[4] = 1.f - omc * (kx * kx + kz * kz);
        R[5] = -s * kx + omc * (ky * kz);
        R[6] = -s * ky + omc * (kx * kz);
        R[7] =  s * kx + omc * (ky * kz);
        R[8] = 1.f - omc * (kx * kx + ky * ky);

        if (j > 0) {
#pragma unroll
            for (int e = 0; e < 9; ++e) {
                float val = R[e] - ((e == 0 || e == 4 || e == 8) ? 1.f : 0.f);
                pfB[(size_t)b * KP + (j - 1) * 9 + e] = f2bf(val);
            }
        }

        int p = kParents[j];
        float tx, ty, tz;
        if (j == 0) { tx = jx[0]; ty = jy[0]; tz = jz[0]; }
        else        { tx = jx[j] - jx[p]; ty = jy[j] - jy[p]; tz = jz[j] - jz[p]; }

        float A[12];
        if (j == 0) {
            A[0] = R[0]; A[1] = R[1]; A[2]  = R[2]; A[3]  = tx;
            A[4] = R[3]; A[5] = R[4]; A[6]  = R[5]; A[7]  = ty;
            A[8] = R[6]; A[9] = R[7]; A[10] = R[8]; A[11] = tz;
        } else {
            float P[12];
#pragma unroll
            for (int e = 0; e < 12; ++e) P[e] = chain[p][e][t];
#pragma unroll
            for (int r = 0; r < 3; ++r) {
#pragma unroll
                for (int cc = 0; cc < 3; ++cc)
                    A[r * 4 + cc] = P[r * 4 + 0] * R[0 * 3 + cc] +
                                    P[r * 4 + 1] * R[1 * 3 + cc] +
                                    P[r * 4 + 2] * R[2 * 3 + cc];
                A[r * 4 + 3] = P[r * 4 + 0] * tx + P[r * 4 + 1] * ty +
                               P[r * 4 + 2] * tz + P[r * 4 + 3];
            }
        }
#pragma unroll
        for (int e = 0; e < 12; ++e) chain[j][e][t] = A[e];

        joints_out[(b * NJ + j) * 3 + 0] = A[3]  + tr0;
        joints_out[(b * NJ + j) * 3 + 1] = A[7]  + tr1;
        joints_out[(b * NJ + j) * 3 + 2] = A[11] + tr2;

        float bx = A[0] * jx[j] + A[1] * jy[j] + A[2]  * jz[j];
        float by = A[4] * jx[j] + A[5] * jy[j] + A[6]  * jz[j];
        float bz = A[8] * jx[j] + A[9] * jy[j] + A[10] * jz[j];
        float relv[12];
        relv[0] = A[0]; relv[1] = A[1]; relv[2]  = A[2];  relv[3]  = A[3]  - bx;
        relv[4] = A[4]; relv[5] = A[5]; relv[6]  = A[6];  relv[7]  = A[7]  - by;
        relv[8] = A[8]; relv[9] = A[9]; relv[10] = A[10]; relv[11] = A[11] - bz;
#pragma unroll
        for (int e = 0; e < 12; ++e)
            relBT[(size_t)(b * 12 + e) * K2 + j] = f2bf(relv[e]);
    }

    // relBT tail: col 24 = transl component (paired with lbswB col24 = 1.0)
#pragma unroll
    for (int e = 0; e < 12; ++e) {
        float tv = (e == 3) ? tr0 : (e == 7) ? tr1 : (e == 11) ? tr2 : 0.f;
        relBT[(size_t)(b * 12 + e) * K2 + 24] = f2bf(tv);
#pragma unroll
        for (int j2 = NJ + 1; j2 < K2; ++j2)
            relBT[(size_t)(b * 12 + e) * K2 + j2] = 0;
    }

    // pfB tail: betas, ones (vtemp hi/lo), zero pad to KP
#pragma unroll
    for (int l = 0; l < NBETA; ++l)
        pfB[(size_t)b * KP + PF + l] = f2bf(bet[l]);
    pfB[(size_t)b * KP + PF + NBETA]     = 0x3F80;
    pfB[(size_t)b * KP + PF + NBETA + 1] = 0x3F80;
    for (int k = PF + NBETA + 2; k < KP; ++k) pfB[(size_t)b * KP + k] = 0;
}

// ---------------------------------------------------------------------------
// k_main v9 = R8's measured-best structure (65 µs): interleaved row-major
// pdT, per-batch-tile GEMM1, barrier-free wave-private LDS, 2-D grid,
// TSW=200 (8B-aligned Tls). Single change vs R8: xls layout [batch][v3local]
// stride 52 -> D-fragment spills as 3x aligned ds_write_b128 (bank-uniform),
// epilogue x-read is 3 contiguous dwords.
// ---------------------------------------------------------------------------
__global__ __launch_bounds__(256, 4) void k_main(
    const unsigned short* __restrict__ pdT,    // (V3PAD, KP) interleaved
    const unsigned short* __restrict__ pfB,    // (BB, KP)
    const unsigned short* __restrict__ lbswB,  // (VPAD, K2)
    const unsigned short* __restrict__ relBT,  // (BB*12, K2)
    float* __restrict__ verts)                 // (B,V,3)
{
    int btg = blockIdx.x;           // 0..15 (4 batch-tiles each)
    int vt  = blockIdx.y;           // 0..107
    int t   = threadIdx.x;
    int lane = t & 63;
    int w    = t >> 6;

    __shared__ float xls[4][16 * XSW];            // 13312 B
    __shared__ unsigned short Tls[4][16 * TSW];   // 25600 B

    int lr  = lane & 15;
    int hi2 = lane >> 4;
    int lk  = hi2 * 8;

    float* xw = &xls[w][0];
    unsigned short* Tw = &Tls[w][0];

    // A-operand: 48 interleaved v3-rows of this wave (vertices w*16..w*16+15)
    const unsigned short* pa = pdT + (size_t)(vt * M3 + w * 48 + lr) * KP + lk;
    s16x8 lf = *(const s16x8*)(lbswB + (size_t)(vt * VTB + w * 16 + lr) * K2 + lk);

    int vglob = vt * VTB + w * 16 + lr;
    bool vok = vglob < VV;

    for (int it = 0; it < NBT; ++it) {
        int b0 = (btg * NBT + it) * 16;

        // ---- GEMM1: D row = v3-sub (s*16+hi2*4+r), col = batch (lr) ----
        {
            f32x4 acc[3];
#pragma unroll
            for (int s = 0; s < 3; ++s) acc[s] = (f32x4){0.f,0.f,0.f,0.f};
            const unsigned short* pb = pfB + (size_t)(b0 + lr) * KP + lk;
#pragma unroll
            for (int ks = 0; ks < KP / 32; ++ks) {
                s16x8 bf = *(const s16x8*)(pb + ks * 32);
                s16x8 a0 = *(const s16x8*)(pa + ks * 32);
                s16x8 a1 = *(const s16x8*)(pa + (size_t)16 * KP + ks * 32);
                s16x8 a2 = *(const s16x8*)(pa + (size_t)32 * KP + ks * 32);
                acc[0] = __builtin_amdgcn_mfma_f32_16x16x32_bf16(a0, bf, acc[0], 0, 0, 0);
                acc[1] = __builtin_amdgcn_mfma_f32_16x16x32_bf16(a1, bf, acc[1], 0, 0, 0);
                acc[2] = __builtin_amdgcn_mfma_f32_16x16x32_bf16(a2, bf, acc[2], 0, 0, 0);
            }
            // xls[batch(lr)][v3local(s*16+hi2*4+r)], r contiguous -> b128
#pragma unroll
            for (int s = 0; s < 3; ++s)
                *(f32x4*)&xw[lr * XSW + s * 16 + hi2 * 4] = acc[s];
        }

        // ---- GEMM2: T[be][vert] -> Tw[vert=lr][be] (per-wave, aligned) ----
#pragma unroll
        for (int mt = 0; mt < 12; ++mt) {
            s16x8 rf = *(const s16x8*)(relBT +
                (size_t)(b0 * 12 + mt * 16 + lr) * K2 + lk);
            f32x4 a2v = {0.f,0.f,0.f,0.f};
            a2v = __builtin_amdgcn_mfma_f32_16x16x32_bf16(rf, lf, a2v, 0, 0, 0);
            union { s16x4 v4; unsigned short u[4]; } pk;
#pragma unroll
            for (int r = 0; r < 4; ++r) pk.u[r] = f2bf(a2v[r]);
            *(s16x4*)&Tw[lr * TSW + mt * 16 + hi2 * 4] = pk.v4;
        }

        // ---- epilogue: vertex w*16+lr, batches hi2+4q (R8 pattern) ----
        if (vok) {
#pragma unroll
            for (int q = 0; q < 4; ++q) {
                int bl = hi2 + 4 * q;

                const float* xp = &xw[bl * XSW + 3 * lr];
                float x0 = xp[0], x1 = xp[1], x2 = xp[2];

                const unsigned short* tp = Tw + lr * TSW + bl * 12;
                uint2 dA = *(const uint2*)tp;
                uint2 dB = *(const uint2*)(tp + 4);
                uint2 dC = *(const uint2*)(tp + 8);
                float T0  = __uint_as_float(dA.x << 16);
                float T1  = __uint_as_float(dA.x & 0xffff0000u);
                float T2  = __uint_as_float(dA.y << 16);
                float T3  = __uint_as_float(dA.y & 0xffff0000u);
                float T4  = __uint_as_float(dB.x << 16);
                float T5  = __uint_as_float(dB.x & 0xffff0000u);
                float T6  = __uint_as_float(dB.y << 16);
                float T7  = __uint_as_float(dB.y & 0xffff0000u);
                float T8  = __uint_as_float(dC.x << 16);
                float T9  = __uint_as_float(dC.x & 0xffff0000u);
                float T10 = __uint_as_float(dC.y << 16);
                float T11 = __uint_as_float(dC.y & 0xffff0000u);

                float o0 = T0 * x0 + T1 * x1 + T2  * x2 + T3;
                float o1 = T4 * x0 + T5 * x1 + T6  * x2 + T7;
                float o2 = T8 * x0 + T9 * x1 + T10 * x2 + T11;

                float* o = verts + ((size_t)(b0 + bl) * VV + vglob) * 3;
                o[0] = o0; o[1] = o1; o[2] = o2;
            }
        }
    }
}

extern "C" void kernel_launch(void* const* d_in, const int* in_sizes, int n_in,
                              void* d_out, int out_size, void* d_ws, size_t ws_size,
                              hipStream_t stream) {
    const float* transl = (const float*)d_in[0];
    const float* orient = (const float*)d_in[1];
    const float* betas  = (const float*)d_in[2];
    const float* bpose  = (const float*)d_in[3];
    const float* vtemp  = (const float*)d_in[4];
    const float* sdirs  = (const float*)d_in[5];
    const float* pdirs  = (const float*)d_in[6];
    const float* jreg   = (const float*)d_in[7];
    const float* lbsw   = (const float*)d_in[8];

    float* out = (float*)d_out;
    float* verts_out  = out;
    float* joints_out = out + (size_t)BB * VV * 3;

    float* ws    = (float*)d_ws;
    float* jpart = ws;                                   // 24*8*33 = 6336 f
    unsigned short* pfB   = (unsigned short*)(ws + 6336);      // B*KP
    unsigned short* pdT   = pfB + (size_t)BB * KP;             // V3PAD*KP
    unsigned short* lbswB = pdT + (size_t)V3PAD * KP;          // VPAD*K2
    unsigned short* relBT = lbswB + (size_t)VPAD * K2;         // B*12*K2

    k_prep_all<<<NBLK_A + NBLK_B + NBLK_C, 256, 0, stream>>>(
        pdirs, sdirs, vtemp, lbsw, jreg, pdT, lbswB, jpart);
    k_batch<<<BB / 32, 32, 0, stream>>>(transl, orient, betas, bpose,
                                        jpart, pfB, relBT, joints_out);
    dim3 g(BB / 16 / NBT, NVT);
    k_main<<<g, 256, 0, stream>>>(pdT, pfB, lbswB, relBT, verts_out);
}